// Round 2
// baseline (194.442 us; speedup 1.0000x reference)
//
#include <hip/hip_runtime.h>

#define BATCH 128
#define VIS   98
#define TOK   196
#define TOK2  392
#define ENC   1024
#define DEC   512
#define MSK   294   // 2*TOK - VIS

#define NWB 256    // (DEC*ENC/4) float4s / 512 threads

#define NGEMM 784  // 4 n-blocks x 196 m-blocks
#define NFILL 1568 // 50176 tokens / 32 tokens per block

typedef __bf16 bf16x8 __attribute__((ext_vector_type(8)));
typedef float  f32x4  __attribute__((ext_vector_type(4)));

__device__ __forceinline__ unsigned short f2bf(float f) {
    union { float f; unsigned u; } c; c.f = f;
    unsigned u = c.u;
    return (unsigned short)((u + 0x7fffu + ((u >> 16) & 1u)) >> 16);
}

// async global -> LDS, 16 B per lane; LDS dest must be wave-uniform base + lane*16
__device__ __forceinline__ void g2lds16(const void* gptr, void* lptr) {
    __builtin_amdgcn_global_load_lds(
        (const __attribute__((address_space(1))) void*)gptr,
        (__attribute__((address_space(3))) void*)lptr, 16, 0, 0);
}

// Small setup dispatch:
//   blocks [0, NWB)        : W  fp32 -> bf16
//   blocks [NWB, NWB+BATCH): build visibility map per batch row
__global__ __launch_bounds__(512) void setup(const float* __restrict__ W,
                                             const int* __restrict__ mids,
                                             unsigned short* __restrict__ wbm,
                                             int* __restrict__ visids,
                                             unsigned char* __restrict__ flags) {
    int bid = blockIdx.x, tid = threadIdx.x;
    if (bid < NWB) {
        int i = bid * 512 + tid;
        float4 f = ((const float4*)W)[i];
        ushort4 o;
        o.x = f2bf(f.x); o.y = f2bf(f.y); o.z = f2bf(f.z); o.w = f2bf(f.w);
        ((ushort4*)wbm)[i] = o;
        return;
    }
    int b = bid - NWB;
    __shared__ unsigned char lf[TOK2];
    __shared__ int wtot[8];
    if (tid < TOK2) lf[tid] = 1;
    __syncthreads();
    if (tid < MSK) lf[mids[b * MSK + tid]] = 0;
    __syncthreads();
    int flag = (tid < TOK2) ? (int)lf[tid] : 0;
    unsigned long long bal = __ballot(flag != 0);
    int lane = tid & 63, wv = tid >> 6;
    int pre = __popcll(bal & ((1ull << lane) - 1ull));
    if (lane == 0) wtot[wv] = __popcll(bal);
    __syncthreads();
    int off = 0;
    for (int i = 0; i < wv; ++i) off += wtot[i];
    if (flag) visids[b * VIS + off + pre] = tid;   // stable: ascending token id
    if (tid < TOK2) flags[b * TOK2 + tid] = lf[tid];
}

// Fused main dispatch:
//   blocks [0, NGEMM)          : xp = x @ W^T + bias, scattered to visible rows
//   blocks [NGEMM, NGEMM+NFILL): masked slots = mask_token + pos + view_embed
// gemm: 64m x 128n tile, BK=64, 256 thr (4 waves 2x2; wave = 32m x 64n, acc[2][4]).
// A: x read fp32 directly, reg-converted (v_cvt_pk_bf16_f32, RNE == f2bf) and
//    ds_write_b128 into the XOR-swizzled layout. B: global_load_lds from bf16 W.
// XOR chunk swizzle: row r stores logical chunk c at slot c ^ (r&7); fragment read
// of chunk (u*4+q) reads slot (u*4+q)^(l16&7).
// mfma_f32_16x16x32_bf16: A lane: row=l&15, k=(l>>4)*8+j ; B lane: col=l&15, same k;
// D lane: col=l&15, row=(l>>4)*4+reg   [m89-verified layout]
__global__ __launch_bounds__(256, 4) void main_fused(
    const float* __restrict__ x,             // (B*V, ENC) fp32
    const unsigned short* __restrict__ wb,   // (DEC, ENC) bf16 bits
    const float* __restrict__ bias,
    const float* __restrict__ mask_token,
    const float* __restrict__ pos,
    const float* __restrict__ ve,
    const int* __restrict__ vis,             // (B*V) -> t
    const unsigned char* __restrict__ flags, // (B*TOK2)
    float* __restrict__ out) {
    __shared__ unsigned short As[64 * 64];   // 8 KB
    __shared__ unsigned short Bs[128 * 64];  // 16 KB
    __shared__ int rowdst[64];
    __shared__ int rowt[64];

    int bid = blockIdx.x;
    int tid = threadIdx.x;

    if (bid >= NGEMM) {
        // ---- masked-fill path: 32 tokens per block, 16 float4 per thread ----
        int fb = bid - NGEMM;
        float4 m = ((const float4*)mask_token)[tid & 127];
        int g0 = fb * 4096 + tid;            // float4 index into out
        #pragma unroll 4
        for (int i = 0; i < 16; ++i) {
            int g = g0 + i * 256;
            int tok = g >> 7;                // global token id in [0, B*TOK2)
            int d4  = g & 127;
            if (flags[tok]) continue;        // visible -> written by gemm path
            int t = tok % TOK2;
            float4 p = ((const float4*)(pos + (size_t)t * DEC))[d4];
            float4 v = ((const float4*)(ve + (t >= TOK ? DEC : 0)))[d4];
            float4 r;
            r.x = m.x + p.x + v.x;
            r.y = m.y + p.y + v.y;
            r.z = m.z + p.z + v.z;
            r.w = m.w + p.w + v.w;
            ((float4*)out)[g] = r;
        }
        return;
    }

    // ---- gemm path ----
    int lane = tid & 63, w = tid >> 6;
    int l16 = lane & 15, q = lane >> 4;
    int wm = w & 1, wn = w >> 1;
    int m0 = (bid >> 2) * 64, n0 = (bid & 3) * 128;

    if (tid < 64) {
        int gr = m0 + tid;
        int t = vis[gr];
        rowt[tid] = t;
        rowdst[tid] = (gr / VIS) * TOK2 + t;
    }

    // staging: thread -> row (tid>>3), chunk slot (tid&7); global chunk c = slot ^ (row&7)
    int c = (tid & 7) ^ ((tid >> 3) & 7);
    const float* gA = x + (size_t)(m0 + (tid >> 3)) * ENC + c * 8;
    const unsigned short* gB = wb + (size_t)(n0 + (tid >> 3)) * ENC + c * 8;
    char* ldsB = (char*)Bs + tid * 16;

    f32x4 acc[2][4];
    #pragma unroll
    for (int i = 0; i < 2; ++i)
        #pragma unroll
        for (int j = 0; j < 4; ++j)
            acc[i][j] = (f32x4){0.f, 0.f, 0.f, 0.f};

    for (int k0 = 0; k0 < ENC; k0 += 64) {
        __syncthreads();
        #pragma unroll
        for (int t = 0; t < 4; ++t)                  // B tile: 128 rows x 64 k bf16
            g2lds16(gB + (size_t)t * 32 * ENC + k0, ldsB + t * 4096);
        #pragma unroll
        for (int t = 0; t < 2; ++t) {                // A tile: 64 rows x 64 k, fp32->bf16
            const float4* ap = (const float4*)(gA + (size_t)t * 32 * ENC + k0);
            float4 f0 = ap[0];
            float4 f1 = ap[1];
            bf16x8 v;
            v[0] = (__bf16)f0.x; v[1] = (__bf16)f0.y;
            v[2] = (__bf16)f0.z; v[3] = (__bf16)f0.w;
            v[4] = (__bf16)f1.x; v[5] = (__bf16)f1.y;
            v[6] = (__bf16)f1.z; v[7] = (__bf16)f1.w;
            *(bf16x8*)((char*)As + t * 4096 + tid * 16) = v;
        }
        __syncthreads();

        #pragma unroll
        for (int u = 0; u < 2; ++u) {                // two k32 substeps
            int slot = ((u * 4 + q) ^ (l16 & 7)) * 16;
            bf16x8 bfrag[4], afrag[2];
            #pragma unroll
            for (int j = 0; j < 4; ++j)
                bfrag[j] = *(const bf16x8*)((const char*)Bs + (wn * 64 + j * 16 + l16) * 128 + slot);
            #pragma unroll
            for (int i = 0; i < 2; ++i)
                afrag[i] = *(const bf16x8*)((const char*)As + (wm * 32 + i * 16 + l16) * 128 + slot);
            #pragma unroll
            for (int i = 0; i < 2; ++i)
                #pragma unroll
                for (int j = 0; j < 4; ++j)
                    acc[i][j] = __builtin_amdgcn_mfma_f32_16x16x32_bf16(afrag[i], bfrag[j], acc[i][j], 0, 0, 0);
        }
    }

    // epilogue: +bias +pos +view_embed, scatter rows to out[b, t, :]
    #pragma unroll
    for (int j = 0; j < 4; ++j) {
        int gcol = n0 + wn * 64 + j * 16 + l16;
        float bc = bias[gcol];
        float v0 = ve[gcol];
        float v1 = ve[DEC + gcol];
        #pragma unroll
        for (int i = 0; i < 2; ++i) {
            #pragma unroll
            for (int r = 0; r < 4; ++r) {
                int rl = wm * 32 + i * 16 + q * 4 + r;
                int t = rowt[rl];
                float val = acc[i][j][r] + bc + pos[(size_t)t * DEC + gcol]
                          + (t >= TOK ? v1 : v0);
                out[(size_t)rowdst[rl] * DEC + gcol] = val;
            }
        }
    }
}

extern "C" void kernel_launch(void* const* d_in, const int* in_sizes, int n_in,
                              void* d_out, int out_size, void* d_ws, size_t ws_size,
                              hipStream_t stream) {
    (void)in_sizes; (void)n_in; (void)out_size; (void)ws_size;
    const float* x    = (const float*)d_in[0];
    const int*   mids = (const int*)d_in[1];
    const float* W    = (const float*)d_in[2];
    const float* bias = (const float*)d_in[3];
    const float* mt   = (const float*)d_in[4];
    const float* pos  = (const float*)d_in[5];
    const float* ve   = (const float*)d_in[6];
    float* out = (float*)d_out;

    // workspace: W bf16 (1 MB) + maps
    unsigned short* wbm = (unsigned short*)d_ws;                     // DEC*ENC bf16
    int* visids = (int*)(wbm + (size_t)DEC * ENC);                   // B*V int
    unsigned char* flags = (unsigned char*)(visids + BATCH * VIS);   // B*392 bytes

    hipLaunchKernelGGL(setup, dim3(NWB + BATCH), dim3(512), 0, stream,
                       W, mids, wbm, visids, flags);
    hipLaunchKernelGGL(main_fused, dim3(NGEMM + NFILL), dim3(256), 0, stream,
                       x, wbm, bias, mt, pos, ve, visids, flags, out);
}

// Round 3
// 193.122 us; speedup vs baseline: 1.0068x; 1.0068x over previous
//
#include <hip/hip_runtime.h>

#define BATCH 128
#define VIS   98
#define TOK   196
#define TOK2  392
#define ENC   1024
#define DEC   512
#define MSK   294   // 2*TOK - VIS

#define NWB 256    // (DEC*ENC/4) float4s / 512 threads

#define NGEMM 784  // 4 n-blocks x 196 m-blocks
#define NFILL 1568 // 50176 tokens / 32 tokens per block

typedef __bf16 bf16x8 __attribute__((ext_vector_type(8)));
typedef float  f32x4  __attribute__((ext_vector_type(4)));

__device__ __forceinline__ unsigned short f2bf(float f) {
    union { float f; unsigned u; } c; c.f = f;
    unsigned u = c.u;
    return (unsigned short)((u + 0x7fffu + ((u >> 16) & 1u)) >> 16);
}

// async global -> LDS, 16 B per lane; LDS dest must be wave-uniform base + lane*16
__device__ __forceinline__ void g2lds16(const void* gptr, void* lptr) {
    __builtin_amdgcn_global_load_lds(
        (const __attribute__((address_space(1))) void*)gptr,
        (__attribute__((address_space(3))) void*)lptr, 16, 0, 0);
}

// Small setup dispatch:
//   blocks [0, NWB)        : W  fp32 -> bf16
//   blocks [NWB, NWB+BATCH): build visibility map per batch row
__global__ __launch_bounds__(512) void setup(const float* __restrict__ W,
                                             const int* __restrict__ mids,
                                             unsigned short* __restrict__ wbm,
                                             int* __restrict__ visids,
                                             unsigned char* __restrict__ flags) {
    int bid = blockIdx.x, tid = threadIdx.x;
    if (bid < NWB) {
        int i = bid * 512 + tid;
        float4 f = ((const float4*)W)[i];
        ushort4 o;
        o.x = f2bf(f.x); o.y = f2bf(f.y); o.z = f2bf(f.z); o.w = f2bf(f.w);
        ((ushort4*)wbm)[i] = o;
        return;
    }
    int b = bid - NWB;
    __shared__ unsigned char lf[TOK2];
    __shared__ int wtot[8];
    if (tid < TOK2) lf[tid] = 1;
    __syncthreads();
    if (tid < MSK) lf[mids[b * MSK + tid]] = 0;
    __syncthreads();
    int flag = (tid < TOK2) ? (int)lf[tid] : 0;
    unsigned long long bal = __ballot(flag != 0);
    int lane = tid & 63, wv = tid >> 6;
    int pre = __popcll(bal & ((1ull << lane) - 1ull));
    if (lane == 0) wtot[wv] = __popcll(bal);
    __syncthreads();
    int off = 0;
    for (int i = 0; i < wv; ++i) off += wtot[i];
    if (flag) visids[b * VIS + off + pre] = tid;   // stable: ascending token id
    if (tid < TOK2) flags[b * TOK2 + tid] = lf[tid];
}

// Fused main dispatch:
//   blocks [0, NGEMM)          : xp = x @ W^T + bias, scattered to visible rows
//   blocks [NGEMM, NGEMM+NFILL): masked slots = mask_token + pos + view_embed
// gemm: 64m x 128n tile, BK=64, 256 thr (4 waves 2x2; wave = 32m x 64n, acc[2][4]).
// A: x staged as RAW FP32 via global_load_lds (async DMA, no reg round-trip);
//    bf16 conversion happens at fragment-read time (RNE cast, == f2bf).
//    fp32 row = 64 f32 = 16 chunks of 16B; 4-bit XOR swizzle: row r stores logical
//    chunk c at slot c ^ (r&15); pre-swizzled global source keeps LDS dest linear.
// B: global_load_lds from pre-converted bf16 W; 3-bit XOR swizzle as before.
// mfma_f32_16x16x32_bf16: A lane: row=l&15, k=(l>>4)*8+j ; B lane: col=l&15, same k;
// D lane: col=l&15, row=(l>>4)*4+reg   [m89-verified layout]
__global__ __launch_bounds__(256, 4) void main_fused(
    const float* __restrict__ x,             // (B*V, ENC) fp32
    const unsigned short* __restrict__ wb,   // (DEC, ENC) bf16 bits
    const float* __restrict__ bias,
    const float* __restrict__ mask_token,
    const float* __restrict__ pos,
    const float* __restrict__ ve,
    const int* __restrict__ vis,             // (B*V) -> t
    const unsigned char* __restrict__ flags, // (B*TOK2)
    float* __restrict__ out) {
    __shared__ float Asf[64 * 64];           // 16 KB (fp32 A tile)
    __shared__ unsigned short Bs[128 * 64];  // 16 KB
    __shared__ int rowdst[64];
    __shared__ int rowt[64];

    int bid = blockIdx.x;
    int tid = threadIdx.x;

    if (bid >= NGEMM) {
        // ---- masked-fill path: 32 tokens per block, 16 float4 per thread ----
        int fb = bid - NGEMM;
        float4 m = ((const float4*)mask_token)[tid & 127];
        int g0 = fb * 4096 + tid;            // float4 index into out
        #pragma unroll 4
        for (int i = 0; i < 16; ++i) {
            int g = g0 + i * 256;
            int tok = g >> 7;                // global token id in [0, B*TOK2)
            int d4  = g & 127;
            if (flags[tok]) continue;        // visible -> written by gemm path
            int t = tok % TOK2;
            float4 p = ((const float4*)(pos + (size_t)t * DEC))[d4];
            float4 v = ((const float4*)(ve + (t >= TOK ? DEC : 0)))[d4];
            float4 r;
            r.x = m.x + p.x + v.x;
            r.y = m.y + p.y + v.y;
            r.z = m.z + p.z + v.z;
            r.w = m.w + p.w + v.w;
            ((float4*)out)[g] = r;
        }
        return;
    }

    // ---- gemm path ----
    int lane = tid & 63, w = tid >> 6;
    int l16 = lane & 15, q = lane >> 4;
    int wm = w & 1, wn = w >> 1;
    int m0 = (bid >> 2) * 64, n0 = (bid & 3) * 128;

    if (tid < 64) {
        int gr = m0 + tid;
        int t = vis[gr];
        rowt[tid] = t;
        rowdst[tid] = (gr / VIS) * TOK2 + t;
    }

    // A staging: thread -> row (tid>>4) within 16-row stripe, slot (tid&15);
    //            global chunk c = slot ^ (row&15); row&15 == tid>>4 for all stripes.
    int arow = tid >> 4;                    // 0..15
    int cA = (tid & 15) ^ arow;             // 16B-chunk index, pre-swizzled
    const float* gA = x + (size_t)(m0 + arow) * ENC + cA * 4;
    char* ldsA = (char*)Asf + tid * 16;
    // B staging: thread -> row (tid>>3), chunk slot (tid&7); global chunk c = slot ^ (row&7)
    int cB = (tid & 7) ^ ((tid >> 3) & 7);
    const unsigned short* gB = wb + (size_t)(n0 + (tid >> 3)) * ENC + cB * 8;
    char* ldsB = (char*)Bs + tid * 16;

    f32x4 acc[2][4];
    #pragma unroll
    for (int i = 0; i < 2; ++i)
        #pragma unroll
        for (int j = 0; j < 4; ++j)
            acc[i][j] = (f32x4){0.f, 0.f, 0.f, 0.f};

    for (int k0 = 0; k0 < ENC; k0 += 64) {
        __syncthreads();
        #pragma unroll
        for (int t = 0; t < 4; ++t)                  // B tile: 128 rows x 64 k bf16
            g2lds16(gB + (size_t)t * 32 * ENC + k0, ldsB + t * 4096);
        #pragma unroll
        for (int t = 0; t < 4; ++t)                  // A tile: 64 rows x 64 k fp32
            g2lds16(gA + (size_t)t * 16 * ENC + k0, ldsA + t * 4096);
        __syncthreads();

        #pragma unroll
        for (int u = 0; u < 2; ++u) {                // two k32 substeps
            int slotB = ((u * 4 + q) ^ (l16 & 7)) * 16;
            int c0 = u * 8 + q * 2;                  // A 16B-chunk pair for this k32
            bf16x8 bfrag[4], afrag[2];
            #pragma unroll
            for (int j = 0; j < 4; ++j)
                bfrag[j] = *(const bf16x8*)((const char*)Bs + (wn * 64 + j * 16 + l16) * 128 + slotB);
            #pragma unroll
            for (int i = 0; i < 2; ++i) {
                const char* rowbase = (const char*)Asf + (wm * 32 + i * 16 + l16) * 256;
                f32x4 lo = *(const f32x4*)(rowbase + ((c0 ^ l16) * 16));
                f32x4 hi = *(const f32x4*)(rowbase + (((c0 + 1) ^ l16) * 16));
                bf16x8 af;
                af[0] = (__bf16)lo[0]; af[1] = (__bf16)lo[1];
                af[2] = (__bf16)lo[2]; af[3] = (__bf16)lo[3];
                af[4] = (__bf16)hi[0]; af[5] = (__bf16)hi[1];
                af[6] = (__bf16)hi[2]; af[7] = (__bf16)hi[3];
                afrag[i] = af;
            }
            #pragma unroll
            for (int i = 0; i < 2; ++i)
                #pragma unroll
                for (int j = 0; j < 4; ++j)
                    acc[i][j] = __builtin_amdgcn_mfma_f32_16x16x32_bf16(afrag[i], bfrag[j], acc[i][j], 0, 0, 0);
        }
    }

    // epilogue: +bias +pos +view_embed, scatter rows to out[b, t, :]
    #pragma unroll
    for (int j = 0; j < 4; ++j) {
        int gcol = n0 + wn * 64 + j * 16 + l16;
        float bc = bias[gcol];
        float v0 = ve[gcol];
        float v1 = ve[DEC + gcol];
        #pragma unroll
        for (int i = 0; i < 2; ++i) {
            #pragma unroll
            for (int r = 0; r < 4; ++r) {
                int rl = wm * 32 + i * 16 + q * 4 + r;
                int t = rowt[rl];
                float val = acc[i][j][r] + bc + pos[(size_t)t * DEC + gcol]
                          + (t >= TOK ? v1 : v0);
                out[(size_t)rowdst[rl] * DEC + gcol] = val;
            }
        }
    }
}

extern "C" void kernel_launch(void* const* d_in, const int* in_sizes, int n_in,
                              void* d_out, int out_size, void* d_ws, size_t ws_size,
                              hipStream_t stream) {
    (void)in_sizes; (void)n_in; (void)out_size; (void)ws_size;
    const float* x    = (const float*)d_in[0];
    const int*   mids = (const int*)d_in[1];
    const float* W    = (const float*)d_in[2];
    const float* bias = (const float*)d_in[3];
    const float* mt   = (const float*)d_in[4];
    const float* pos  = (const float*)d_in[5];
    const float* ve   = (const float*)d_in[6];
    float* out = (float*)d_out;

    // workspace: W bf16 (1 MB) + maps
    unsigned short* wbm = (unsigned short*)d_ws;                     // DEC*ENC bf16
    int* visids = (int*)(wbm + (size_t)DEC * ENC);                   // B*V int
    unsigned char* flags = (unsigned char*)(visids + BATCH * VIS);   // B*392 bytes

    hipLaunchKernelGGL(setup, dim3(NWB + BATCH), dim3(512), 0, stream,
                       W, mids, wbm, visids, flags);
    hipLaunchKernelGGL(main_fused, dim3(NGEMM + NFILL), dim3(256), 0, stream,
                       x, wbm, bias, mt, pos, ve, visids, flags, out);
}

// Round 4
// 188.988 us; speedup vs baseline: 1.0289x; 1.0219x over previous
//
#include <hip/hip_runtime.h>

#define BATCH 128
#define VIS   98
#define TOK   196
#define TOK2  392
#define ENC   1024
#define DEC   512
#define MSK   294   // 2*TOK - VIS

#define NWB 256    // (DEC*ENC/4) float4s / 512 threads

#define NGEMM 784  // 4 n-blocks x 196 m-blocks
#define NFILL 1568 // 50176 tokens / 32 tokens per block

typedef __bf16 bf16x8 __attribute__((ext_vector_type(8)));
typedef float  f32x4  __attribute__((ext_vector_type(4)));

__device__ __forceinline__ unsigned short f2bf(float f) {
    union { float f; unsigned u; } c; c.f = f;
    unsigned u = c.u;
    return (unsigned short)((u + 0x7fffu + ((u >> 16) & 1u)) >> 16);
}

// async global -> LDS, 16 B per lane; LDS dest must be wave-uniform base + lane*16
__device__ __forceinline__ void g2lds16(const void* gptr, void* lptr) {
    __builtin_amdgcn_global_load_lds(
        (const __attribute__((address_space(1))) void*)gptr,
        (__attribute__((address_space(3))) void*)lptr, 16, 0, 0);
}

// Small setup dispatch:
//   blocks [0, NWB)        : W  fp32 -> bf16
//   blocks [NWB, NWB+BATCH): build visibility map per batch row
__global__ __launch_bounds__(512) void setup(const float* __restrict__ W,
                                             const int* __restrict__ mids,
                                             unsigned short* __restrict__ wbm,
                                             int* __restrict__ visids,
                                             unsigned char* __restrict__ flags) {
    int bid = blockIdx.x, tid = threadIdx.x;
    if (bid < NWB) {
        int i = bid * 512 + tid;
        float4 f = ((const float4*)W)[i];
        ushort4 o;
        o.x = f2bf(f.x); o.y = f2bf(f.y); o.z = f2bf(f.z); o.w = f2bf(f.w);
        ((ushort4*)wbm)[i] = o;
        return;
    }
    int b = bid - NWB;
    __shared__ unsigned char lf[TOK2];
    __shared__ int wtot[8];
    if (tid < TOK2) lf[tid] = 1;
    __syncthreads();
    if (tid < MSK) lf[mids[b * MSK + tid]] = 0;
    __syncthreads();
    int flag = (tid < TOK2) ? (int)lf[tid] : 0;
    unsigned long long bal = __ballot(flag != 0);
    int lane = tid & 63, wv = tid >> 6;
    int pre = __popcll(bal & ((1ull << lane) - 1ull));
    if (lane == 0) wtot[wv] = __popcll(bal);
    __syncthreads();
    int off = 0;
    for (int i = 0; i < wv; ++i) off += wtot[i];
    if (flag) visids[b * VIS + off + pre] = tid;   // stable: ascending token id
    if (tid < TOK2) flags[b * TOK2 + tid] = lf[tid];
}

// Fused main dispatch:
//   blocks [0, NGEMM)          : xp = x @ W^T + bias, scattered to visible rows
//   blocks [NGEMM, NGEMM+NFILL): masked slots = mask_token + pos + view_embed
// gemm: 64m x 128n tile, BK=64, 256 thr (4 waves 2x2; wave = 32m x 64n, acc[2][4]).
// PIPELINED: double-buffered LDS (A fp32 16KBx2, B bf16 16KBx2). Per K-step:
//   stage tile t+1 into half cur^1 -> s_waitcnt vmcnt(8) (tile-t loads = oldest 8,
//   tile-t+1's 8 stay in flight ACROSS the raw s_barrier) -> compute tile t.
//   Raw __builtin_amdgcn_s_barrier(), never __syncthreads(), inside the loop.
// XCD co-location: the 4 n-blocks of each m-block share bid%8 -> same XCD L2,
//   so the x row-panel is fetched ~once instead of 4x (MSHR/L2 coalescing).
// A staged raw fp32; bf16 cvt at fragment-read (RNE cast == f2bf). 4-bit XOR
//   swizzle on A chunks, 3-bit on B chunks; pre-swizzled global src, linear LDS dest.
// mfma_f32_16x16x32_bf16: A lane: row=l&15, k=(l>>4)*8+j ; B lane: col=l&15, same k;
// D lane: col=l&15, row=(l>>4)*4+reg   [m89-verified layout]
__global__ __launch_bounds__(256, 2) void main_fused(
    const float* __restrict__ x,             // (B*V, ENC) fp32
    const unsigned short* __restrict__ wb,   // (DEC, ENC) bf16 bits
    const float* __restrict__ bias,
    const float* __restrict__ mask_token,
    const float* __restrict__ pos,
    const float* __restrict__ ve,
    const int* __restrict__ vis,             // (B*V) -> t
    const unsigned char* __restrict__ flags, // (B*TOK2)
    float* __restrict__ out) {
    __shared__ float Asf[2][64 * 64];            // 2 x 16 KB (fp32 A tile)
    __shared__ unsigned short Bs[2][128 * 64];   // 2 x 16 KB
    __shared__ int rowdst[64];
    __shared__ int rowt[64];

    int bid = blockIdx.x;
    int tid = threadIdx.x;

    if (bid >= NGEMM) {
        // ---- masked-fill path: 32 tokens per block, 16 float4 per thread ----
        int fb = bid - NGEMM;
        float4 m = ((const float4*)mask_token)[tid & 127];
        int g0 = fb * 4096 + tid;            // float4 index into out
        #pragma unroll 4
        for (int i = 0; i < 16; ++i) {
            int g = g0 + i * 256;
            int tok = g >> 7;                // global token id in [0, B*TOK2)
            int d4  = g & 127;
            if (flags[tok]) continue;        // visible -> written by gemm path
            int t = tok % TOK2;
            float4 p = ((const float4*)(pos + (size_t)t * DEC))[d4];
            float4 v = ((const float4*)(ve + (t >= TOK ? DEC : 0)))[d4];
            float4 r;
            r.x = m.x + p.x + v.x;
            r.y = m.y + p.y + v.y;
            r.z = m.z + p.z + v.z;
            r.w = m.w + p.w + v.w;
            ((float4*)out)[g] = r;
        }
        return;
    }

    // ---- gemm path ----
    int lane = tid & 63, w = tid >> 6;
    int l16 = lane & 15, q = lane >> 4;
    int wm = w & 1, wn = w >> 1;

    // XCD co-location: for bid<768, mb = (bid&7) + 8*(bid>>5), nb = (bid>>3)&3
    //   -> all 4 n-blocks of an m-block have the same bid%8 (same XCD).
    // Tail (bid in [768,784)): plain 4x4 mapping for mb 192..195.
    int mb, nb;
    if (bid < 768) { mb = (bid & 7) + ((bid >> 5) << 3); nb = (bid >> 3) & 3; }
    else           { int ii = bid - 768; mb = 192 + (ii & 3); nb = ii >> 2; }
    int m0 = mb * 64, n0 = nb * 128;

    if (tid < 64) {
        int gr = m0 + tid;
        int t = vis[gr];
        rowt[tid] = t;
        rowdst[tid] = (gr / VIS) * TOK2 + t;
    }

    // A staging: thread -> row (tid>>4) within 16-row stripe, slot (tid&15);
    //            global chunk c = slot ^ (row&15); row&15 == tid>>4 for all stripes.
    int arow = tid >> 4;                    // 0..15
    int cA = (tid & 15) ^ arow;             // 16B-chunk index, pre-swizzled
    const float* gA = x + (size_t)(m0 + arow) * ENC + cA * 4;
    // B staging: thread -> row (tid>>3), chunk slot (tid&7); global chunk c = slot ^ (row&7)
    int cB = (tid & 7) ^ ((tid >> 3) & 7);
    const unsigned short* gB = wb + (size_t)(n0 + (tid >> 3)) * ENC + cB * 8;

    f32x4 acc[2][4];
    #pragma unroll
    for (int i = 0; i < 2; ++i)
        #pragma unroll
        for (int j = 0; j < 4; ++j)
            acc[i][j] = (f32x4){0.f, 0.f, 0.f, 0.f};

    // prologue: stage tile 0 into half 0 (drained by the one __syncthreads below,
    // which also publishes rowt/rowdst)
    {
        char* lA = (char*)(&Asf[0][0]) + tid * 16;
        char* lB = (char*)(&Bs[0][0]) + tid * 16;
        #pragma unroll
        for (int tt = 0; tt < 4; ++tt)
            g2lds16(gB + (size_t)tt * 32 * ENC, lB + tt * 4096);
        #pragma unroll
        for (int tt = 0; tt < 4; ++tt)
            g2lds16(gA + (size_t)tt * 16 * ENC, lA + tt * 4096);
    }
    __syncthreads();

    for (int t = 0; t < 16; ++t) {
        int cur = t & 1;
        if (t < 15) {
            int k0 = (t + 1) << 6;
            char* lA = (char*)(&Asf[cur ^ 1][0]) + tid * 16;
            char* lB = (char*)(&Bs[cur ^ 1][0]) + tid * 16;
            #pragma unroll
            for (int tt = 0; tt < 4; ++tt)
                g2lds16(gB + (size_t)tt * 32 * ENC + k0, lB + tt * 4096);
            #pragma unroll
            for (int tt = 0; tt < 4; ++tt)
                g2lds16(gA + (size_t)tt * 16 * ENC + k0, lA + tt * 4096);
            __builtin_amdgcn_sched_barrier(0);
            asm volatile("s_waitcnt vmcnt(8)" ::: "memory");   // tile t done; t+1 in flight
        } else {
            __builtin_amdgcn_sched_barrier(0);
            asm volatile("s_waitcnt vmcnt(0)" ::: "memory");   // last tile done
        }
        __builtin_amdgcn_s_barrier();                          // tile t visible to all waves

        const char* Ab = (const char*)(&Asf[cur][0]);
        const char* Bb = (const char*)(&Bs[cur][0]);
        #pragma unroll
        for (int u = 0; u < 2; ++u) {                // two k32 substeps
            int slotB = ((u * 4 + q) ^ (l16 & 7)) * 16;
            int c0 = u * 8 + q * 2;                  // A 16B-chunk pair for this k32
            bf16x8 bfrag[4], afrag[2];
            #pragma unroll
            for (int j = 0; j < 4; ++j)
                bfrag[j] = *(const bf16x8*)(Bb + (wn * 64 + j * 16 + l16) * 128 + slotB);
            #pragma unroll
            for (int i = 0; i < 2; ++i) {
                const char* rowbase = Ab + (wm * 32 + i * 16 + l16) * 256;
                f32x4 lo = *(const f32x4*)(rowbase + ((c0 ^ l16) * 16));
                f32x4 hi = *(const f32x4*)(rowbase + (((c0 + 1) ^ l16) * 16));
                bf16x8 af;
                af[0] = (__bf16)lo[0]; af[1] = (__bf16)lo[1];
                af[2] = (__bf16)lo[2]; af[3] = (__bf16)lo[3];
                af[4] = (__bf16)hi[0]; af[5] = (__bf16)hi[1];
                af[6] = (__bf16)hi[2]; af[7] = (__bf16)hi[3];
                afrag[i] = af;
            }
            #pragma unroll
            for (int i = 0; i < 2; ++i)
                #pragma unroll
                for (int j = 0; j < 4; ++j)
                    acc[i][j] = __builtin_amdgcn_mfma_f32_16x16x32_bf16(afrag[i], bfrag[j], acc[i][j], 0, 0, 0);
        }
        __builtin_amdgcn_s_barrier();    // all reads of half cur consumed before overwrite
    }

    // epilogue: +bias +pos +view_embed, scatter rows to out[b, t, :]
    #pragma unroll
    for (int j = 0; j < 4; ++j) {
        int gcol = n0 + wn * 64 + j * 16 + l16;
        float bc = bias[gcol];
        float v0 = ve[gcol];
        float v1 = ve[DEC + gcol];
        #pragma unroll
        for (int i = 0; i < 2; ++i) {
            #pragma unroll
            for (int r = 0; r < 4; ++r) {
                int rl = wm * 32 + i * 16 + q * 4 + r;
                int t = rowt[rl];
                float val = acc[i][j][r] + bc + pos[(size_t)t * DEC + gcol]
                          + (t >= TOK ? v1 : v0);
                out[(size_t)rowdst[rl] * DEC + gcol] = val;
            }
        }
    }
}

extern "C" void kernel_launch(void* const* d_in, const int* in_sizes, int n_in,
                              void* d_out, int out_size, void* d_ws, size_t ws_size,
                              hipStream_t stream) {
    (void)in_sizes; (void)n_in; (void)out_size; (void)ws_size;
    const float* x    = (const float*)d_in[0];
    const int*   mids = (const int*)d_in[1];
    const float* W    = (const float*)d_in[2];
    const float* bias = (const float*)d_in[3];
    const float* mt   = (const float*)d_in[4];
    const float* pos  = (const float*)d_in[5];
    const float* ve   = (const float*)d_in[6];
    float* out = (float*)d_out;

    // workspace: W bf16 (1 MB) + maps
    unsigned short* wbm = (unsigned short*)d_ws;                     // DEC*ENC bf16
    int* visids = (int*)(wbm + (size_t)DEC * ENC);                   // B*V int
    unsigned char* flags = (unsigned char*)(visids + BATCH * VIS);   // B*392 bytes

    hipLaunchKernelGGL(setup, dim3(NWB + BATCH), dim3(512), 0, stream,
                       W, mids, wbm, visids, flags);
    hipLaunchKernelGGL(main_fused, dim3(NGEMM + NFILL), dim3(256), 0, stream,
                       x, wbm, bias, mt, pos, ve, visids, flags, out);
}

// Round 5
// 187.321 us; speedup vs baseline: 1.0380x; 1.0089x over previous
//
#include <hip/hip_runtime.h>

#define BATCH 128
#define VIS   98
#define TOK   196
#define TOK2  392
#define ENC   1024
#define DEC   512
#define MSK   294   // 2*TOK - VIS

#define NWB 256    // (DEC*ENC/4) float4s / 512 threads

#define NGEMM 784  // 4 n-blocks x 196 m-blocks
#define NFILL 1568 // 50176 tokens / 32 tokens per block

typedef __bf16 bf16x8 __attribute__((ext_vector_type(8)));
typedef float  f32x4  __attribute__((ext_vector_type(4)));

__device__ __forceinline__ unsigned short f2bf(float f) {
    union { float f; unsigned u; } c; c.f = f;
    unsigned u = c.u;
    return (unsigned short)((u + 0x7fffu + ((u >> 16) & 1u)) >> 16);
}

// async global -> LDS, 16 B per lane; LDS dest must be wave-uniform base + lane*16
__device__ __forceinline__ void g2lds16(const void* gptr, void* lptr) {
    __builtin_amdgcn_global_load_lds(
        (const __attribute__((address_space(1))) void*)gptr,
        (__attribute__((address_space(3))) void*)lptr, 16, 0, 0);
}

// Small setup dispatch:
//   blocks [0, NWB)        : W  fp32 -> bf16
//   blocks [NWB, NWB+BATCH): build visibility map per batch row
__global__ __launch_bounds__(512) void setup(const float* __restrict__ W,
                                             const int* __restrict__ mids,
                                             unsigned short* __restrict__ wbm,
                                             int* __restrict__ visids,
                                             unsigned char* __restrict__ flags) {
    int bid = blockIdx.x, tid = threadIdx.x;
    if (bid < NWB) {
        int i = bid * 512 + tid;
        float4 f = ((const float4*)W)[i];
        ushort4 o;
        o.x = f2bf(f.x); o.y = f2bf(f.y); o.z = f2bf(f.z); o.w = f2bf(f.w);
        ((ushort4*)wbm)[i] = o;
        return;
    }
    int b = bid - NWB;
    __shared__ unsigned char lf[TOK2];
    __shared__ int wtot[8];
    if (tid < TOK2) lf[tid] = 1;
    __syncthreads();
    if (tid < MSK) lf[mids[b * MSK + tid]] = 0;
    __syncthreads();
    int flag = (tid < TOK2) ? (int)lf[tid] : 0;
    unsigned long long bal = __ballot(flag != 0);
    int lane = tid & 63, wv = tid >> 6;
    int pre = __popcll(bal & ((1ull << lane) - 1ull));
    if (lane == 0) wtot[wv] = __popcll(bal);
    __syncthreads();
    int off = 0;
    for (int i = 0; i < wv; ++i) off += wtot[i];
    if (flag) visids[b * VIS + off + pre] = tid;   // stable: ascending token id
    if (tid < TOK2) flags[b * TOK2 + tid] = lf[tid];
}

// Fused main dispatch:
//   blocks [0, NGEMM)          : xp = x @ W^T + bias, scattered to visible rows
//   blocks [NGEMM, NGEMM+NFILL): masked slots = mask_token + pos + view_embed
// gemm: 64m x 128n tile, BK=64, 256 thr (4 waves 2x2; wave = 32m x 64n, acc[2][4]).
// A in LDS as BF16 (r1 geometry: 8 KB/buf, fragment path identical to r1), staged
//   via registers: load 4x float4 of x fp32 for tile t+1 BEFORE compute(t)
//   (issue-early), cvt+ds_write_b128 AFTER compute(t) (write-late, T14). RNE cast
//   == f2bf -> numerics identical.
// B via global_load_lds from pre-converted bf16 W (proven path), double-buffered.
// One barrier per iter; every wave drains vmcnt(0)+lgkmcnt(0) BEFORE the barrier,
//   so all waves' loads/writes for tile t+1 are landed before any wave computes it.
//   WAR on each buffer half is separated by one full barrier interval.
// LDS 48.5 KB -> 3 blocks/CU (12 waves) for gemm AND fill blocks.
// XCD co-location: 4 n-blocks of each m-block share bid%8 (FETCH 110->39 MB, r4).
// 3-bit XOR chunk swizzle both operands: row r stores logical chunk c at slot
//   c^(r&7); fragment read of chunk (u*4+q) reads slot (u*4+q)^(l16&7).
// mfma_f32_16x16x32_bf16: A lane: row=l&15, k=(l>>4)*8+j ; B lane: col=l&15, same k;
// D lane: col=l&15, row=(l>>4)*4+reg   [m89-verified layout]
__global__ __launch_bounds__(256, 3) void main_fused(
    const float* __restrict__ x,             // (B*V, ENC) fp32
    const unsigned short* __restrict__ wb,   // (DEC, ENC) bf16 bits
    const float* __restrict__ bias,
    const float* __restrict__ mask_token,
    const float* __restrict__ pos,
    const float* __restrict__ ve,
    const int* __restrict__ vis,             // (B*V) -> t
    const unsigned char* __restrict__ flags, // (B*TOK2)
    float* __restrict__ out) {
    __shared__ unsigned short Abf[2][64 * 64];   // 2 x 8 KB (bf16 A tile)
    __shared__ unsigned short Bs[2][128 * 64];   // 2 x 16 KB
    __shared__ int rowdst[64];
    __shared__ int rowt[64];

    int bid = blockIdx.x;
    int tid = threadIdx.x;

    if (bid >= NGEMM) {
        // ---- masked-fill path: 32 tokens per block, 16 float4 per thread ----
        int fb = bid - NGEMM;
        float4 m = ((const float4*)mask_token)[tid & 127];
        int g0 = fb * 4096 + tid;            // float4 index into out
        #pragma unroll 4
        for (int i = 0; i < 16; ++i) {
            int g = g0 + i * 256;
            int tok = g >> 7;                // global token id in [0, B*TOK2)
            int d4  = g & 127;
            if (flags[tok]) continue;        // visible -> written by gemm path
            int t = tok % TOK2;
            float4 p = ((const float4*)(pos + (size_t)t * DEC))[d4];
            float4 v = ((const float4*)(ve + (t >= TOK ? DEC : 0)))[d4];
            float4 r;
            r.x = m.x + p.x + v.x;
            r.y = m.y + p.y + v.y;
            r.z = m.z + p.z + v.z;
            r.w = m.w + p.w + v.w;
            ((float4*)out)[g] = r;
        }
        return;
    }

    // ---- gemm path ----
    int lane = tid & 63, w = tid >> 6;
    int l16 = lane & 15, q = lane >> 4;
    int wm = w & 1, wn = w >> 1;

    // XCD co-location: for bid<768, mb = (bid&7) + 8*(bid>>5), nb = (bid>>3)&3
    int mb, nb;
    if (bid < 768) { mb = (bid & 7) + ((bid >> 5) << 3); nb = (bid >> 3) & 3; }
    else           { int ii = bid - 768; mb = 192 + (ii & 3); nb = ii >> 2; }
    int m0 = mb * 64, n0 = nb * 128;

    if (tid < 64) {
        int gr = m0 + tid;
        int t = vis[gr];
        rowt[tid] = t;
        rowdst[tid] = (gr / VIS) * TOK2 + t;
    }

    // A reg-staging: thread handles rows r0 = tid>>3 and r0+32, slot sA = tid&7.
    // logical chunk c = sA ^ (r0&7)  (rows r0 and r0+32 share low 3 bits).
    int r0 = tid >> 3, sA = tid & 7;
    int cAc = sA ^ (r0 & 7);
    const float* gA0 = x + (size_t)(m0 + r0) * ENC + cAc * 8;
    const float* gA1 = gA0 + (size_t)32 * ENC;
    int aW0 = r0 * 128 + sA * 16;            // byte offset of this thread's chunk, row r0
    int aW1 = aW0 + 32 * 128;                // row r0+32
    // B staging: thread -> row (tid>>3), chunk slot (tid&7); global chunk c = slot ^ (row&7)
    int cB = (tid & 7) ^ ((tid >> 3) & 7);
    const unsigned short* gB = wb + (size_t)(n0 + (tid >> 3)) * ENC + cB * 8;

    f32x4 acc[2][4];
    #pragma unroll
    for (int i = 0; i < 2; ++i)
        #pragma unroll
        for (int j = 0; j < 4; ++j)
            acc[i][j] = (f32x4){0.f, 0.f, 0.f, 0.f};

    // prologue: tile 0 -> buffer 0
    {
        float4 p00 = ((const float4*)gA0)[0];
        float4 p01 = ((const float4*)gA0)[1];
        float4 p10 = ((const float4*)gA1)[0];
        float4 p11 = ((const float4*)gA1)[1];
        char* lB = (char*)(&Bs[0][0]) + tid * 16;
        #pragma unroll
        for (int tt = 0; tt < 4; ++tt)
            g2lds16(gB + (size_t)tt * 32 * ENC, lB + tt * 4096);
        bf16x8 v0, v1;
        v0[0] = (__bf16)p00.x; v0[1] = (__bf16)p00.y; v0[2] = (__bf16)p00.z; v0[3] = (__bf16)p00.w;
        v0[4] = (__bf16)p01.x; v0[5] = (__bf16)p01.y; v0[6] = (__bf16)p01.z; v0[7] = (__bf16)p01.w;
        v1[0] = (__bf16)p10.x; v1[1] = (__bf16)p10.y; v1[2] = (__bf16)p10.z; v1[3] = (__bf16)p10.w;
        v1[4] = (__bf16)p11.x; v1[5] = (__bf16)p11.y; v1[6] = (__bf16)p11.z; v1[7] = (__bf16)p11.w;
        *(bf16x8*)((char*)(&Abf[0][0]) + aW0) = v0;
        *(bf16x8*)((char*)(&Abf[0][0]) + aW1) = v1;
    }
    __syncthreads();   // drains prologue vmem+lds, publishes rowt/rowdst + tile 0

    for (int t = 0; t < 16; ++t) {
        int c = t & 1;
        float4 n00, n01, n10, n11;
        if (t < 15) {
            int k0 = (t + 1) << 6;
            // issue-early: A(t+1) reg loads, then B(t+1) gload_lds into Bs[c^1]
            n00 = ((const float4*)(gA0 + k0))[0];
            n01 = ((const float4*)(gA0 + k0))[1];
            n10 = ((const float4*)(gA1 + k0))[0];
            n11 = ((const float4*)(gA1 + k0))[1];
            char* lB = (char*)(&Bs[c ^ 1][0]) + tid * 16;
            #pragma unroll
            for (int tt = 0; tt < 4; ++tt)
                g2lds16(gB + (size_t)tt * 32 * ENC + k0, lB + tt * 4096);
        }
        __builtin_amdgcn_sched_barrier(0);   // pin issues above the compute phase

        // compute tile t (fragment path identical to r1)
        const char* Ab = (const char*)(&Abf[c][0]);
        const char* Bb = (const char*)(&Bs[c][0]);
        #pragma unroll
        for (int u = 0; u < 2; ++u) {                // two k32 substeps
            int slot = ((u * 4 + q) ^ (l16 & 7)) * 16;
            bf16x8 bfrag[4], afrag[2];
            #pragma unroll
            for (int j = 0; j < 4; ++j)
                bfrag[j] = *(const bf16x8*)(Bb + (wn * 64 + j * 16 + l16) * 128 + slot);
            #pragma unroll
            for (int i = 0; i < 2; ++i)
                afrag[i] = *(const bf16x8*)(Ab + (wm * 32 + i * 16 + l16) * 128 + slot);
            #pragma unroll
            for (int i = 0; i < 2; ++i)
                #pragma unroll
                for (int j = 0; j < 4; ++j)
                    acc[i][j] = __builtin_amdgcn_mfma_f32_16x16x32_bf16(afrag[i], bfrag[j], acc[i][j], 0, 0, 0);
        }

        // write-late: cvt A(t+1) and store into Abf[c^1]
        if (t < 15) {
            bf16x8 v0, v1;
            v0[0] = (__bf16)n00.x; v0[1] = (__bf16)n00.y; v0[2] = (__bf16)n00.z; v0[3] = (__bf16)n00.w;
            v0[4] = (__bf16)n01.x; v0[5] = (__bf16)n01.y; v0[6] = (__bf16)n01.z; v0[7] = (__bf16)n01.w;
            v1[0] = (__bf16)n10.x; v1[1] = (__bf16)n10.y; v1[2] = (__bf16)n10.z; v1[3] = (__bf16)n10.w;
            v1[4] = (__bf16)n11.x; v1[5] = (__bf16)n11.y; v1[6] = (__bf16)n11.z; v1[7] = (__bf16)n11.w;
            *(bf16x8*)((char*)(&Abf[c ^ 1][0]) + aW0) = v0;
            *(bf16x8*)((char*)(&Abf[c ^ 1][0]) + aW1) = v1;
        }

        // drain everything this wave owes for tile t+1, then one barrier.
        __builtin_amdgcn_sched_barrier(0);
        asm volatile("s_waitcnt vmcnt(0) lgkmcnt(0)" ::: "memory");
        __builtin_amdgcn_sched_barrier(0);
        __builtin_amdgcn_s_barrier();
    }

    // epilogue: +bias +pos +view_embed, scatter rows to out[b, t, :]
    #pragma unroll
    for (int j = 0; j < 4; ++j) {
        int gcol = n0 + wn * 64 + j * 16 + l16;
        float bc = bias[gcol];
        float v0 = ve[gcol];
        float v1 = ve[DEC + gcol];
        #pragma unroll
        for (int i = 0; i < 2; ++i) {
            #pragma unroll
            for (int r = 0; r < 4; ++r) {
                int rl = wm * 32 + i * 16 + q * 4 + r;
                int t = rowt[rl];
                float val = acc[i][j][r] + bc + pos[(size_t)t * DEC + gcol]
                          + (t >= TOK ? v1 : v0);
                out[(size_t)rowdst[rl] * DEC + gcol] = val;
            }
        }
    }
}

extern "C" void kernel_launch(void* const* d_in, const int* in_sizes, int n_in,
                              void* d_out, int out_size, void* d_ws, size_t ws_size,
                              hipStream_t stream) {
    (void)in_sizes; (void)n_in; (void)out_size; (void)ws_size;
    const float* x    = (const float*)d_in[0];
    const int*   mids = (const int*)d_in[1];
    const float* W    = (const float*)d_in[2];
    const float* bias = (const float*)d_in[3];
    const float* mt   = (const float*)d_in[4];
    const float* pos  = (const float*)d_in[5];
    const float* ve   = (const float*)d_in[6];
    float* out = (float*)d_out;

    // workspace: W bf16 (1 MB) + maps
    unsigned short* wbm = (unsigned short*)d_ws;                     // DEC*ENC bf16
    int* visids = (int*)(wbm + (size_t)DEC * ENC);                   // B*V int
    unsigned char* flags = (unsigned char*)(visids + BATCH * VIS);   // B*392 bytes

    hipLaunchKernelGGL(setup, dim3(NWB + BATCH), dim3(512), 0, stream,
                       W, mids, wbm, visids, flags);
    hipLaunchKernelGGL(main_fused, dim3(NGEMM + NFILL), dim3(256), 0, stream,
                       x, wbm, bias, mt, pos, ve, visids, flags, out);
}

// Round 6
// 184.241 us; speedup vs baseline: 1.0554x; 1.0167x over previous
//
#include <hip/hip_runtime.h>

#define BATCH 128
#define VIS   98
#define TOK   196
#define TOK2  392
#define ENC   1024
#define DEC   512
#define MSK   294   // 2*TOK - VIS

#define NXB 6272   // (B*V*ENC/4) float4s / 512 threads
#define NWB 256    // (DEC*ENC/4)  float4s / 512 threads

#define NGEMM 784  // 4 n-blocks x 196 m-blocks
#define NFILL 1568 // 50176 tokens / 32 tokens per block

typedef __bf16 bf16x8 __attribute__((ext_vector_type(8)));
typedef float  f32x4  __attribute__((ext_vector_type(4)));

__device__ __forceinline__ unsigned short f2bf(float f) {
    union { float f; unsigned u; } c; c.f = f;
    unsigned u = c.u;
    return (unsigned short)((u + 0x7fffu + ((u >> 16) & 1u)) >> 16);
}

// async global -> LDS, 16 B per lane; LDS dest must be wave-uniform base + lane*16
__device__ __forceinline__ void g2lds16(const void* gptr, void* lptr) {
    __builtin_amdgcn_global_load_lds(
        (const __attribute__((address_space(1))) void*)gptr,
        (__attribute__((address_space(3))) void*)lptr, 16, 0, 0);
}

// One fused setup dispatch (r1 version — the xb round-trip is a WIN: it converts
// the GEMM's A-read from cold-HBM fp32 (~900cy, unhideable at 1-tile lookahead;
// r2-r5 all 70-80us) to L3/L2-warm bf16 (r1: ~40us). Do not remove again.):
//   blocks [0, NXB)          : x  fp32 -> bf16
//   blocks [NXB, NXB+NWB)    : W  fp32 -> bf16
//   blocks [NXB+NWB, +BATCH) : build visibility map per batch row
__global__ __launch_bounds__(512) void setup(const float* __restrict__ x,
                                             const float* __restrict__ W,
                                             const int* __restrict__ mids,
                                             unsigned short* __restrict__ xb,
                                             unsigned short* __restrict__ wbm,
                                             int* __restrict__ visids,
                                             unsigned char* __restrict__ flags) {
    int bid = blockIdx.x, tid = threadIdx.x;
    if (bid < NXB + NWB) {
        const float* src = (bid < NXB) ? x : W;
        unsigned short* dst = (bid < NXB) ? xb : wbm;
        int i = (bid < NXB ? bid : bid - NXB) * 512 + tid;
        float4 f = ((const float4*)src)[i];
        ushort4 o;
        o.x = f2bf(f.x); o.y = f2bf(f.y); o.z = f2bf(f.z); o.w = f2bf(f.w);
        ((ushort4*)dst)[i] = o;
        return;
    }
    int b = bid - NXB - NWB;
    __shared__ unsigned char lf[TOK2];
    __shared__ int wtot[8];
    if (tid < TOK2) lf[tid] = 1;
    __syncthreads();
    if (tid < MSK) lf[mids[b * MSK + tid]] = 0;
    __syncthreads();
    int flag = (tid < TOK2) ? (int)lf[tid] : 0;
    unsigned long long bal = __ballot(flag != 0);
    int lane = tid & 63, wv = tid >> 6;
    int pre = __popcll(bal & ((1ull << lane) - 1ull));
    if (lane == 0) wtot[wv] = __popcll(bal);
    __syncthreads();
    int off = 0;
    for (int i = 0; i < wv; ++i) off += wtot[i];
    if (flag) visids[b * VIS + off + pre] = tid;   // stable: ascending token id
    if (tid < TOK2) flags[b * TOK2 + tid] = lf[tid];
}

// Fused main dispatch, INTERLEAVED: bid%3==0 -> gemm block g=bid/3,
// else fill block f = bid - bid/3 - 1. Mixes MFMA-bound and write-BW-bound
// blocks on each CU so pipes overlap (was: two contiguous ranges).
// gemm: 64m x 128n tile, BK=64, 256 thr (4 waves 2x2; wave = 32m x 64n, acc[2][4]).
//   r1 core: both operands bf16 via global_load_lds, single-buffered, __syncthreads.
//   XCD co-location on g: 4 n-blocks of each m-block share g%8 -> same XCD L2
//   (r4: FETCH 110->39 MB). Co-location survives interleave: xcd = (3g)%8 is a
//   function of g%8 only.
// XOR chunk swizzle: row r stores logical chunk c at slot c ^ (r&7); fragment read
//   of chunk (u*4+q) reads slot (u*4+q)^(l16&7).
// mfma_f32_16x16x32_bf16: A lane: row=l&15, k=(l>>4)*8+j ; B lane: col=l&15, same k;
// D lane: col=l&15, row=(l>>4)*4+reg   [m89-verified layout]
__global__ __launch_bounds__(256, 6) void main_fused(
    const unsigned short* __restrict__ xb,   // (B*V, ENC) bf16 bits
    const unsigned short* __restrict__ wb,   // (DEC, ENC) bf16 bits
    const float* __restrict__ bias,
    const float* __restrict__ mask_token,
    const float* __restrict__ pos,
    const float* __restrict__ ve,
    const int* __restrict__ vis,             // (B*V) -> t
    const unsigned char* __restrict__ flags, // (B*TOK2)
    float* __restrict__ out) {
    __shared__ unsigned short As[64 * 64];   // 8 KB
    __shared__ unsigned short Bs[128 * 64];  // 16 KB
    __shared__ int rowdst[64];
    __shared__ int rowt[64];

    int bid = blockIdx.x;
    int tid = threadIdx.x;

    if (bid % 3 != 0) {
        // ---- masked-fill path: 32 tokens per block, 16 float4 per thread ----
        int fb = bid - bid / 3 - 1;          // 0..NFILL-1
        float4 m = ((const float4*)mask_token)[tid & 127];
        int g0 = fb * 4096 + tid;            // float4 index into out
        #pragma unroll 4
        for (int i = 0; i < 16; ++i) {
            int g = g0 + i * 256;
            int tok = g >> 7;                // global token id in [0, B*TOK2)
            int d4  = g & 127;
            if (flags[tok]) continue;        // visible -> written by gemm path
            int t = tok % TOK2;
            float4 p = ((const float4*)(pos + (size_t)t * DEC))[d4];
            float4 v = ((const float4*)(ve + (t >= TOK ? DEC : 0)))[d4];
            float4 r;
            r.x = m.x + p.x + v.x;
            r.y = m.y + p.y + v.y;
            r.z = m.z + p.z + v.z;
            r.w = m.w + p.w + v.w;
            ((float4*)out)[g] = r;
        }
        return;
    }

    // ---- gemm path ----
    int g = bid / 3;                         // 0..NGEMM-1
    int lane = tid & 63, w = tid >> 6;
    int l16 = lane & 15, q = lane >> 4;
    int wm = w & 1, wn = w >> 1;

    // XCD co-location: for g<768, mb = (g&7) + 8*(g>>5), nb = (g>>3)&3
    //   -> all 4 n-blocks of an m-block share g%8 (same XCD). Tail: plain map.
    int mb, nb;
    if (g < 768) { mb = (g & 7) + ((g >> 5) << 3); nb = (g >> 3) & 3; }
    else         { int ii = g - 768; mb = 192 + (ii & 3); nb = ii >> 2; }
    int m0 = mb * 64, n0 = nb * 128;

    if (tid < 64) {
        int gr = m0 + tid;
        int t = vis[gr];
        rowt[tid] = t;
        rowdst[tid] = (gr / VIS) * TOK2 + t;
    }

    // staging: thread -> row (tid>>3), chunk slot (tid&7); global chunk c = slot ^ (row&7)
    int c = (tid & 7) ^ ((tid >> 3) & 7);
    const unsigned short* gA = xb + (size_t)(m0 + (tid >> 3)) * ENC + c * 8;
    const unsigned short* gB = wb + (size_t)(n0 + (tid >> 3)) * ENC + c * 8;
    char* ldsA = (char*)As + tid * 16;
    char* ldsB = (char*)Bs + tid * 16;

    f32x4 acc[2][4];
    #pragma unroll
    for (int i = 0; i < 2; ++i)
        #pragma unroll
        for (int j = 0; j < 4; ++j)
            acc[i][j] = (f32x4){0.f, 0.f, 0.f, 0.f};

    for (int k0 = 0; k0 < ENC; k0 += 64) {
        __syncthreads();
        #pragma unroll
        for (int t = 0; t < 2; ++t)                  // A tile: 64 rows x 64 k bf16
            g2lds16(gA + (size_t)t * 32 * ENC + k0, ldsA + t * 4096);
        #pragma unroll
        for (int t = 0; t < 4; ++t)                  // B tile: 128 rows x 64 k bf16
            g2lds16(gB + (size_t)t * 32 * ENC + k0, ldsB + t * 4096);
        __syncthreads();

        #pragma unroll
        for (int u = 0; u < 2; ++u) {                // two k32 substeps
            int slot = ((u * 4 + q) ^ (l16 & 7)) * 16;
            bf16x8 bfrag[4], afrag[2];
            #pragma unroll
            for (int j = 0; j < 4; ++j)
                bfrag[j] = *(const bf16x8*)((const char*)Bs + (wn * 64 + j * 16 + l16) * 128 + slot);
            #pragma unroll
            for (int i = 0; i < 2; ++i)
                afrag[i] = *(const bf16x8*)((const char*)As + (wm * 32 + i * 16 + l16) * 128 + slot);
            #pragma unroll
            for (int i = 0; i < 2; ++i)
                #pragma unroll
                for (int j = 0; j < 4; ++j)
                    acc[i][j] = __builtin_amdgcn_mfma_f32_16x16x32_bf16(afrag[i], bfrag[j], acc[i][j], 0, 0, 0);
        }
    }

    // epilogue: +bias +pos +view_embed, scatter rows to out[b, t, :]
    #pragma unroll
    for (int j = 0; j < 4; ++j) {
        int gcol = n0 + wn * 64 + j * 16 + l16;
        float bc = bias[gcol];
        float v0 = ve[gcol];
        float v1 = ve[DEC + gcol];
        #pragma unroll
        for (int i = 0; i < 2; ++i) {
            #pragma unroll
            for (int r = 0; r < 4; ++r) {
                int rl = wm * 32 + i * 16 + q * 4 + r;
                int t = rowt[rl];
                float val = acc[i][j][r] + bc + pos[(size_t)t * DEC + gcol]
                          + (t >= TOK ? v1 : v0);
                out[(size_t)rowdst[rl] * DEC + gcol] = val;
            }
        }
    }
}

extern "C" void kernel_launch(void* const* d_in, const int* in_sizes, int n_in,
                              void* d_out, int out_size, void* d_ws, size_t ws_size,
                              hipStream_t stream) {
    (void)in_sizes; (void)n_in; (void)out_size; (void)ws_size;
    const float* x    = (const float*)d_in[0];
    const int*   mids = (const int*)d_in[1];
    const float* W    = (const float*)d_in[2];
    const float* bias = (const float*)d_in[3];
    const float* mt   = (const float*)d_in[4];
    const float* pos  = (const float*)d_in[5];
    const float* ve   = (const float*)d_in[6];
    float* out = (float*)d_out;

    // workspace: x bf16 (25.7 MB) + W bf16 (1 MB) + maps
    unsigned short* xb = (unsigned short*)d_ws;                      // B*V*ENC bf16
    unsigned short* wbm = xb + (size_t)BATCH * VIS * ENC;            // DEC*ENC bf16
    int* visids = (int*)(wbm + (size_t)DEC * ENC);                   // B*V int
    unsigned char* flags = (unsigned char*)(visids + BATCH * VIS);   // B*392 bytes

    hipLaunchKernelGGL(setup, dim3(NXB + NWB + BATCH), dim3(512), 0, stream,
                       x, W, mids, xb, wbm, visids, flags);
    hipLaunchKernelGGL(main_fused, dim3(NGEMM + NFILL), dim3(256), 0, stream,
                       xb, wbm, bias, mt, pos, ve, visids, flags, out);
}

// Round 7
// 178.889 us; speedup vs baseline: 1.0869x; 1.0299x over previous
//
#include <hip/hip_runtime.h>

#define BATCH 128
#define VIS   98
#define TOK   196
#define TOK2  392
#define ENC   1024
#define DEC   512
#define MSK   294   // 2*TOK - VIS

#define NXB 6272   // (B*V*ENC/4) float4s / 512 threads
#define NWB 256    // (DEC*ENC/4)  float4s / 512 threads
#define NFILL 1176 // 37632 masked tokens / 32 per block

#define NGEMM 784  // 4 n-blocks x 196 m-blocks

typedef __bf16 bf16x8 __attribute__((ext_vector_type(8)));
typedef float  f32x4  __attribute__((ext_vector_type(4)));

__device__ __forceinline__ unsigned short f2bf(float f) {
    union { float f; unsigned u; } c; c.f = f;
    unsigned u = c.u;
    return (unsigned short)((u + 0x7fffu + ((u >> 16) & 1u)) >> 16);
}

// async global -> LDS, 16 B per lane; LDS dest must be wave-uniform base + lane*16
__device__ __forceinline__ void g2lds16(const void* gptr, void* lptr) {
    __builtin_amdgcn_global_load_lds(
        (const __attribute__((address_space(1))) void*)gptr,
        (__attribute__((address_space(3))) void*)lptr, 16, 0, 0);
}

// Launch 1 — everything except the GEMM, all mutually independent, BW-bound:
//   blocks [0, NXB)               : x fp32 -> bf16   (xb round-trip is a WIN: it
//     converts the GEMM's A-read from cold-HBM fp32 (~900cy, unhideable; r2-r5
//     all 70-80us) to L2-warm bf16 (r1: fast). Do not remove again.)
//   blocks [NXB, +NWB)            : W fp32 -> bf16
//   blocks [NXB+NWB, +BATCH)      : visibility map per batch row (visids only;
//     flags dropped — fill no longer needs them)
//   blocks [NXB+NWB+BATCH, +NFILL): masked fill DIRECT FROM mids (masked ids are
//     exactly mids[b,:] — no dependency on the vis pass). 32 tokens/block,
//     token ids staged in LDS, writes coalesced float4.
__global__ __launch_bounds__(512) void setup_fill(
    const float* __restrict__ x,
    const float* __restrict__ W,
    const int* __restrict__ mids,
    const float* __restrict__ mask_token,
    const float* __restrict__ pos,
    const float* __restrict__ ve,
    unsigned short* __restrict__ xb,
    unsigned short* __restrict__ wbm,
    int* __restrict__ visids,
    float* __restrict__ out) {
    int bid = blockIdx.x, tid = threadIdx.x;
    if (bid < NXB + NWB) {
        const float* src = (bid < NXB) ? x : W;
        unsigned short* dst = (bid < NXB) ? xb : wbm;
        int i = (bid < NXB ? bid : bid - NXB) * 512 + tid;
        float4 f = ((const float4*)src)[i];
        ushort4 o;
        o.x = f2bf(f.x); o.y = f2bf(f.y); o.z = f2bf(f.z); o.w = f2bf(f.w);
        ((ushort4*)dst)[i] = o;
        return;
    }
    if (bid < NXB + NWB + BATCH) {
        // ---- visibility map ----
        int b = bid - NXB - NWB;
        __shared__ unsigned char lf[TOK2];
        __shared__ int wtot[8];
        if (tid < TOK2) lf[tid] = 1;
        __syncthreads();
        if (tid < MSK) lf[mids[b * MSK + tid]] = 0;
        __syncthreads();
        int flag = (tid < TOK2) ? (int)lf[tid] : 0;
        unsigned long long bal = __ballot(flag != 0);
        int lane = tid & 63, wv = tid >> 6;
        int pre = __popcll(bal & ((1ull << lane) - 1ull));
        if (lane == 0) wtot[wv] = __popcll(bal);
        __syncthreads();
        int off = 0;
        for (int i = 0; i < wv; ++i) off += wtot[i];
        if (flag) visids[b * VIS + off + pre] = tid;   // stable: ascending token id
        return;
    }
    // ---- masked fill from mids: 32 tokens per block ----
    int fb = bid - (NXB + NWB + BATCH);
    __shared__ int base[32];   // out float4 base per token
    __shared__ int tsl[32];    // token id within [0, 2T) per token
    if (tid < 32) {
        int fid = fb * 32 + tid;          // fid = b*MSK + m (row-major)
        int b = fid / MSK;
        int t = mids[fid];
        tsl[tid] = t;
        base[tid] = (b * TOK2 + t) * 128;
    }
    __syncthreads();
    float4 m = ((const float4*)mask_token)[tid & 127];
    #pragma unroll
    for (int i = 0; i < 8; ++i) {
        int g = i * 512 + tid;
        int ltok = g >> 7;                // d4 = g & 127 == tid & 127 (512 % 128 == 0)
        int d4 = tid & 127;
        int t = tsl[ltok];
        float4 p = ((const float4*)pos)[t * 128 + d4];
        float4 v = ((const float4*)(ve + (t >= TOK ? DEC : 0)))[d4];
        float4 r;
        r.x = m.x + p.x + v.x;
        r.y = m.y + p.y + v.y;
        r.z = m.z + p.z + v.z;
        r.w = m.w + p.w + v.w;
        ((float4*)out)[base[ltok] + d4] = r;
    }
}

// Launch 2 — pure GEMM: xp = x @ W^T + bias, scattered to out[b, visids[b,v], :]
//   (+pos +view_embed). 64m x 128n tile, BK=64, 256 thr (4 waves 2x2; wave =
//   32m x 64n, acc[2][4]). r1 core: both operands bf16 via global_load_lds,
//   single-buffered, __syncthreads — TLP at 4 blocks/CU does the latency hiding
//   (r4/r5 dbuf+vmcnt experiments were all slower; don't re-add).
// XCD co-location: 4 n-blocks of each m-block share bid%8 -> same XCD L2
//   (r4: FETCH 110->39 MB); per-XCD xb slice ~3.2 MB fits 4 MB L2.
// XOR chunk swizzle: row r stores logical chunk c at slot c ^ (r&7); fragment
//   read of chunk (u*4+q) reads slot (u*4+q)^(l16&7).
// mfma_f32_16x16x32_bf16: A lane: row=l&15, k=(l>>4)*8+j ; B lane: col=l&15,
//   same k; D lane: col=l&15, row=(l>>4)*4+reg   [m89-verified layout]
__global__ __launch_bounds__(256, 4) void gemm_scatter(
    const unsigned short* __restrict__ xb,   // (B*V, ENC) bf16 bits
    const unsigned short* __restrict__ wb,   // (DEC, ENC) bf16 bits
    const float* __restrict__ bias,
    const float* __restrict__ pos,
    const float* __restrict__ ve,
    const int* __restrict__ vis,             // (B*V) -> t
    float* __restrict__ out) {
    __shared__ unsigned short As[64 * 64];   // 8 KB
    __shared__ unsigned short Bs[128 * 64];  // 16 KB
    __shared__ int rowdst[64];
    __shared__ int rowt[64];

    int bid = blockIdx.x;
    int tid = threadIdx.x;
    int lane = tid & 63, w = tid >> 6;
    int l16 = lane & 15, q = lane >> 4;
    int wm = w & 1, wn = w >> 1;

    // XCD co-location: for bid<768, mb = (bid&7) + 8*(bid>>5), nb = (bid>>3)&3
    //   -> all 4 n-blocks of an m-block share bid%8 (same XCD). Tail: plain map.
    int mb, nb;
    if (bid < 768) { mb = (bid & 7) + ((bid >> 5) << 3); nb = (bid >> 3) & 3; }
    else           { int ii = bid - 768; mb = 192 + (ii & 3); nb = ii >> 2; }
    int m0 = mb * 64, n0 = nb * 128;

    if (tid < 64) {
        int gr = m0 + tid;
        int t = vis[gr];
        rowt[tid] = t;
        rowdst[tid] = (gr / VIS) * TOK2 + t;
    }

    // staging: thread -> row (tid>>3), chunk slot (tid&7); global chunk c = slot ^ (row&7)
    int c = (tid & 7) ^ ((tid >> 3) & 7);
    const unsigned short* gA = xb + (size_t)(m0 + (tid >> 3)) * ENC + c * 8;
    const unsigned short* gB = wb + (size_t)(n0 + (tid >> 3)) * ENC + c * 8;
    char* ldsA = (char*)As + tid * 16;
    char* ldsB = (char*)Bs + tid * 16;

    f32x4 acc[2][4];
    #pragma unroll
    for (int i = 0; i < 2; ++i)
        #pragma unroll
        for (int j = 0; j < 4; ++j)
            acc[i][j] = (f32x4){0.f, 0.f, 0.f, 0.f};

    for (int k0 = 0; k0 < ENC; k0 += 64) {
        __syncthreads();
        #pragma unroll
        for (int t = 0; t < 2; ++t)                  // A tile: 64 rows x 64 k bf16
            g2lds16(gA + (size_t)t * 32 * ENC + k0, ldsA + t * 4096);
        #pragma unroll
        for (int t = 0; t < 4; ++t)                  // B tile: 128 rows x 64 k bf16
            g2lds16(gB + (size_t)t * 32 * ENC + k0, ldsB + t * 4096);
        __syncthreads();

        #pragma unroll
        for (int u = 0; u < 2; ++u) {                // two k32 substeps
            int slot = ((u * 4 + q) ^ (l16 & 7)) * 16;
            bf16x8 bfrag[4], afrag[2];
            #pragma unroll
            for (int j = 0; j < 4; ++j)
                bfrag[j] = *(const bf16x8*)((const char*)Bs + (wn * 64 + j * 16 + l16) * 128 + slot);
            #pragma unroll
            for (int i = 0; i < 2; ++i)
                afrag[i] = *(const bf16x8*)((const char*)As + (wm * 32 + i * 16 + l16) * 128 + slot);
            #pragma unroll
            for (int i = 0; i < 2; ++i)
                #pragma unroll
                for (int j = 0; j < 4; ++j)
                    acc[i][j] = __builtin_amdgcn_mfma_f32_16x16x32_bf16(afrag[i], bfrag[j], acc[i][j], 0, 0, 0);
        }
    }

    // epilogue: +bias +pos +view_embed, scatter rows to out[b, t, :]
    #pragma unroll
    for (int j = 0; j < 4; ++j) {
        int gcol = n0 + wn * 64 + j * 16 + l16;
        float bc = bias[gcol];
        float v0 = ve[gcol];
        float v1 = ve[DEC + gcol];
        #pragma unroll
        for (int i = 0; i < 2; ++i) {
            #pragma unroll
            for (int r = 0; r < 4; ++r) {
                int rl = wm * 32 + i * 16 + q * 4 + r;
                int t = rowt[rl];
                float val = acc[i][j][r] + bc + pos[(size_t)t * DEC + gcol]
                          + (t >= TOK ? v1 : v0);
                out[(size_t)rowdst[rl] * DEC + gcol] = val;
            }
        }
    }
}

extern "C" void kernel_launch(void* const* d_in, const int* in_sizes, int n_in,
                              void* d_out, int out_size, void* d_ws, size_t ws_size,
                              hipStream_t stream) {
    (void)in_sizes; (void)n_in; (void)out_size; (void)ws_size;
    const float* x    = (const float*)d_in[0];
    const int*   mids = (const int*)d_in[1];
    const float* W    = (const float*)d_in[2];
    const float* bias = (const float*)d_in[3];
    const float* mt   = (const float*)d_in[4];
    const float* pos  = (const float*)d_in[5];
    const float* ve   = (const float*)d_in[6];
    float* out = (float*)d_out;

    // workspace: x bf16 (25.7 MB) + W bf16 (1 MB) + visids
    unsigned short* xb = (unsigned short*)d_ws;                      // B*V*ENC bf16
    unsigned short* wbm = xb + (size_t)BATCH * VIS * ENC;            // DEC*ENC bf16
    int* visids = (int*)(wbm + (size_t)DEC * ENC);                   // B*V int

    hipLaunchKernelGGL(setup_fill, dim3(NXB + NWB + BATCH + NFILL), dim3(512), 0, stream,
                       x, W, mids, mt, pos, ve, xb, wbm, visids, out);
    hipLaunchKernelGGL(gemm_scatter, dim3(NGEMM), dim3(256), 0, stream,
                       xb, wbm, bias, pos, ve, visids, out);
}